// Round 9
// baseline (138.053 us; speedup 1.0000x reference)
//
#include <hip/hip_runtime.h>

// ---------- small helpers ----------
typedef __attribute__((ext_vector_type(8))) short bf16x8;
typedef __attribute__((ext_vector_type(4))) float f32x4;
typedef __attribute__((ext_vector_type(8))) unsigned short u16x8;

typedef const __attribute__((address_space(1))) void* as1cv;
typedef __attribute__((address_space(3))) void* as3v;

__device__ __forceinline__ unsigned short f2bf(float f) {
    union { float f; unsigned u; } x; x.f = f;
    unsigned r = x.u + 0x7FFFu + ((x.u >> 16) & 1u);   // RNE
    return (unsigned short)(r >> 16);
}
__device__ __forceinline__ float bf2f(unsigned short u) {
    union { unsigned u; float f; } x; x.u = ((unsigned)u) << 16; return x.f;
}

// ---------- 1. both weights (1024x1024 f32) -> transposed bf16, one launch ----------
__global__ void k_transpose_bf16(const float* __restrict__ W1, unsigned short* __restrict__ W1t,
                                 const float* __restrict__ W2, unsigned short* __restrict__ W2t) {
    const int rows = 1024, cols = 1024;
    const float* W = blockIdx.z ? W2 : W1;
    unsigned short* Wt = blockIdx.z ? W2t : W1t;
    __shared__ float tile[64][65];
    int r0 = blockIdx.y * 64, c0 = blockIdx.x * 64;
    #pragma unroll
    for (int i = 0; i < 16; ++i) {
        int idx = threadIdx.x + i * 256;
        int r = idx >> 6, c = idx & 63;
        tile[r][c] = W[(long)(r0 + r) * cols + (c0 + c)];
    }
    __syncthreads();
    #pragma unroll
    for (int i = 0; i < 16; ++i) {
        int idx = threadIdx.x + i * 256;
        int r = idx >> 6, c = idx & 63;
        Wt[(long)(c0 + r) * rows + (r0 + c)] = f2bf(tile[c][r]);
    }
}

// ---------- 2. GEMM 256x256 8-phase — R4 structure + optional fused fp32-A cvt ----------
// A_FP32=1: A is read as fp32 (x) via reg-staging (4x global_load_dwordx4 in the
// A-phases), converted to bf16 and ds_write_b128'd into the SAME swizzled LDS
// layout at P4/P8 (chunk = (lane&7)^segRow on the write side == the read XOR;
// rule-21 both-sides). vmcnt(4) ledger re-derived and unchanged.
template<int OUT_BF16, int DO_COLSUM, int A_FP32>
__global__ __launch_bounds__(512, 2) void k_gemm256(
    const unsigned short* __restrict__ A,   // bf16 A (if !A_FP32)
    const float* __restrict__ Af,           // fp32 A (if A_FP32)
    const unsigned short* __restrict__ Bt,
    const float* __restrict__ bias,
    void* __restrict__ C,
    float* __restrict__ totals,
    int M, int N, int K)
{
    __shared__ unsigned short lds[2][4][8192];
    const int tid  = threadIdx.x;
    const int lane = tid & 63;
    const int w    = tid >> 6;          // wave 0..7
    const int wm   = w >> 2;            // 0..1 (M half)
    const int wn   = w & 3;             // 0..3 (N quarter)

    const int nwg = gridDim.x;
    const int cpx = nwg >> 3;
    const int wg  = (blockIdx.x & 7) * cpx + (blockIdx.x >> 3);
    const int nblks = N >> 8;
    const int mblk = wg / nblks, nblk = wg % nblks;
    const long m0 = (long)mblk << 8, n0 = (long)nblk << 8;

    const int segRow  = lane >> 3;
    const long segColE = (long)(((lane & 7) ^ segRow) << 3);
    const int colf = (lane & 7) * 8;    // natural fp32 col base (A_FP32 path)

    const int rr = lane & 15, cc = lane >> 4;
    const int smask = (rr & 7) << 4;
    const int colSwz0 = (((cc * 16) ^ smask) >> 1);
    const int colSwz1 = (((64 + cc * 16) ^ smask) >> 1);

    auto stage = [&](int buf, int slot, const unsigned short* src, long rowBase, int kt) {
        #pragma unroll
        for (int g = 0; g < 2; ++g) {
            const int s = w + g * 8;
            const unsigned short* gp = src + (rowBase + s * 8 + segRow) * (long)K
                                           + (long)kt * 64 + segColE;
            __builtin_amdgcn_global_load_lds((as1cv)gp,
                (as3v)(&lds[buf][slot][s * 512 + lane * 8]), 16, 0, 0);
        }
    };

    // fp32-A reg staging (A_FP32 path)
    float4 aR0[4], aR1[4];
    auto aload = [&](float4* r, long rowBase, int kt) {
        #pragma unroll
        for (int g = 0; g < 2; ++g) {
            const int s = w + g * 8;
            const float* gp = Af + (rowBase + s * 8 + segRow) * (long)K
                                 + (long)kt * 64 + colf;
            r[2 * g]     = *(const float4*)(gp);
            r[2 * g + 1] = *(const float4*)(gp + 4);
        }
    };
    auto awrite = [&](int buf, int slot, float4* r) {
        #pragma unroll
        for (int g = 0; g < 2; ++g) {
            const int s = w + g * 8;
            uint4 pk;
            pk.x = (unsigned)f2bf(r[2*g].x)   | ((unsigned)f2bf(r[2*g].y)   << 16);
            pk.y = (unsigned)f2bf(r[2*g].z)   | ((unsigned)f2bf(r[2*g].w)   << 16);
            pk.z = (unsigned)f2bf(r[2*g+1].x) | ((unsigned)f2bf(r[2*g+1].y) << 16);
            pk.w = (unsigned)f2bf(r[2*g+1].z) | ((unsigned)f2bf(r[2*g+1].w) << 16);
            *(uint4*)(&lds[buf][slot][s * 512 + segRow * 64 + (((lane & 7) ^ segRow) << 3)]) = pk;
        }
    };

    // acc[mi][nj]: mi = row 16-group (wave's 128 rows), nj = col 16-group (64 cols)
    f32x4 acc[8][4];
    #pragma unroll
    for (int i = 0; i < 8; ++i)
        #pragma unroll
        for (int j = 0; j < 4; ++j)
            acc[i][j] = (f32x4){0.f, 0.f, 0.f, 0.f};

    bf16x8 bfrag[4][2];
    const int bRowBase = (wn & 1) * 64;
    const int NK = K >> 6;
    const int ITERS = K >> 7;

#define VM4   asm volatile("s_waitcnt vmcnt(4)" ::: "memory")
#define PHASE(BUF, Q, STAGES, VMW) do {                                              \
    bf16x8 af0_0, af0_1, af1_0, af1_1;                                               \
    { const unsigned short* Ah = &lds[BUF][wm][0];                                   \
      af0_0 = *(const bf16x8*)(Ah + ((Q)*32 + rr) * 64 + colSwz0);                   \
      af0_1 = *(const bf16x8*)(Ah + ((Q)*32 + rr) * 64 + colSwz1);                   \
      af1_0 = *(const bf16x8*)(Ah + ((Q)*32 + 16 + rr) * 64 + colSwz0);              \
      af1_1 = *(const bf16x8*)(Ah + ((Q)*32 + 16 + rr) * 64 + colSwz1); }            \
    if ((Q) == 0) { const unsigned short* Bh = &lds[BUF][2 + (wn >> 1)][0];          \
      _Pragma("unroll")                                                              \
      for (int nj = 0; nj < 4; ++nj) {                                               \
        bfrag[nj][0] = *(const bf16x8*)(Bh + (bRowBase + nj*16 + rr) * 64 + colSwz0);\
        bfrag[nj][1] = *(const bf16x8*)(Bh + (bRowBase + nj*16 + rr) * 64 + colSwz1);\
      } }                                                                            \
    STAGES;                                                                          \
    VMW;                                                                             \
    __builtin_amdgcn_s_barrier();                                                    \
    asm volatile("s_waitcnt lgkmcnt(0)" ::: "memory");                               \
    __builtin_amdgcn_sched_barrier(0);                                               \
    __builtin_amdgcn_s_setprio(1);                                                   \
    _Pragma("unroll")                                                                \
    for (int nj = 0; nj < 4; ++nj) {                                                 \
      acc[2*(Q)][nj]   = __builtin_amdgcn_mfma_f32_16x16x32_bf16(af0_0, bfrag[nj][0], acc[2*(Q)][nj],   0,0,0); \
      acc[2*(Q)][nj]   = __builtin_amdgcn_mfma_f32_16x16x32_bf16(af0_1, bfrag[nj][1], acc[2*(Q)][nj],   0,0,0); \
      acc[2*(Q)+1][nj] = __builtin_amdgcn_mfma_f32_16x16x32_bf16(af1_0, bfrag[nj][0], acc[2*(Q)+1][nj], 0,0,0); \
      acc[2*(Q)+1][nj] = __builtin_amdgcn_mfma_f32_16x16x32_bf16(af1_1, bfrag[nj][1], acc[2*(Q)+1][nj], 0,0,0); \
    }                                                                                \
    __builtin_amdgcn_s_setprio(0);                                                   \
    __builtin_amdgcn_s_barrier();                                                    \
} while (0)

    if constexpr (A_FP32) {
        // prologue: A kt0 via regs; B kt0+kt1 via gload_lds
        aload(aR0, m0, 0);
        aload(aR1, m0 + 128, 0);
        stage(0, 2, Bt, n0,       0);
        stage(0, 3, Bt, n0 + 128, 0);
        stage(1, 2, Bt, n0,       1);
        stage(1, 3, Bt, n0 + 128, 1);
        asm volatile("s_waitcnt vmcnt(8)" ::: "memory");   // retire A kt0 reg-loads
        awrite(0, 0, aR0);
        awrite(0, 1, aR1);
        asm volatile("s_waitcnt vmcnt(4) lgkmcnt(0)" ::: "memory");  // B kt0 landed, writes drained
        __builtin_amdgcn_s_barrier();

        for (int it = 0; it < ITERS; ++it) {
            const int kt1 = 2 * it + 1;
            int kt2 = 2 * it + 2; if (kt2 >= NK) kt2 = 0;
            int kt3 = 2 * it + 3; if (kt3 >= NK) kt3 = 1;

            PHASE(0, 0, aload(aR0, m0,       kt1), );
            PHASE(0, 1, aload(aR1, m0 + 128, kt1), );
            PHASE(0, 2, { stage(0, 2, Bt, n0, kt2); stage(0, 3, Bt, n0 + 128, kt2); }, );
            PHASE(0, 3, { VM4; awrite(1, 0, aR0); awrite(1, 1, aR1); }, );
            PHASE(1, 0, aload(aR0, m0,       kt2), );
            PHASE(1, 1, aload(aR1, m0 + 128, kt2), );
            PHASE(1, 2, { stage(1, 2, Bt, n0, kt3); stage(1, 3, Bt, n0 + 128, kt3); }, );
            PHASE(1, 3, { VM4; awrite(0, 0, aR0); awrite(0, 1, aR1); }, );
        }
    } else {
        stage(0, 0, A,  m0,       0);
        stage(0, 1, A,  m0 + 128, 0);
        stage(0, 2, Bt, n0,       0);
        stage(0, 3, Bt, n0 + 128, 0);
        stage(1, 2, Bt, n0,       1);
        stage(1, 3, Bt, n0 + 128, 1);
        VM4;
        __builtin_amdgcn_s_barrier();

        for (int it = 0; it < ITERS; ++it) {
            const int kt1 = 2 * it + 1;
            int kt2 = 2 * it + 2; if (kt2 >= NK) kt2 = 0;
            int kt3 = 2 * it + 3; if (kt3 >= NK) kt3 = 1;

            PHASE(0, 0, stage(1, 0, A,  m0,       kt1), );
            PHASE(0, 1, stage(1, 1, A,  m0 + 128, kt1), );
            PHASE(0, 2, { stage(0, 2, Bt, n0, kt2); stage(0, 3, Bt, n0 + 128, kt2); }, );
            PHASE(0, 3, , VM4);
            PHASE(1, 0, stage(0, 0, A,  m0,       kt2), );
            PHASE(1, 1, stage(0, 1, A,  m0 + 128, kt2), );
            PHASE(1, 2, { stage(1, 2, Bt, n0, kt3); stage(1, 3, Bt, n0 + 128, kt3); }, );
            PHASE(1, 3, , VM4);
        }
    }
#undef PHASE
#undef VM4

    // epilogue — EXACT R4 order: mi-outer, nj-mid, jj-inner (store order is load-bearing)
    float cs[4] = {0.f, 0.f, 0.f, 0.f};
    #pragma unroll
    for (int mi = 0; mi < 8; ++mi) {
        const long rowb = m0 + wm * 128 + mi * 16 + cc * 4;
        #pragma unroll
        for (int nj = 0; nj < 4; ++nj) {
            const long col = n0 + wn * 64 + nj * 16 + rr;
            const float bv = bias[col];
            #pragma unroll
            for (int jj = 0; jj < 4; ++jj) {
                const float v = acc[mi][nj][jj] + bv;
                if (DO_COLSUM) cs[nj] += v;
                if (OUT_BF16) ((unsigned short*)C)[(rowb + jj) * N + col] = f2bf(v);
                else          ((float*)C)[(rowb + jj) * N + col] = v;
            }
        }
    }
    if (DO_COLSUM) {
        const int b = (int)(m0 >> 11);      // 2048 rows per batch
        #pragma unroll
        for (int nj = 0; nj < 4; ++nj) {
            float c0 = cs[nj];
            c0 += __shfl_xor(c0, 16, 64);
            c0 += __shfl_xor(c0, 32, 64);
            if (cc == 0)
                atomicAdd(totals + b * 1024 + n0 + wn * 64 + nj * 16 + rr, c0);
        }
    }
}

// ---------- 3. FSMN v4: burst-load window + taps in regs, 32 outputs/thread ----------
#define FS_ROWS 167   // 128 + 39
__global__ __launch_bounds__(256, 2) void k_fsmn(
    const unsigned short* __restrict__ p,   // (B*T, 1024) bf16
    const float* __restrict__ mw,           // (41, 1024) fp32
    const float* __restrict__ total,        // (B, 1024) fp32
    unsigned short* __restrict__ p2,        // (B*T, 1024) bf16
    int T)
{
    __shared__ unsigned short sp[FS_ROWS][64];   // [c][d], t = t0 + c - 39
    __shared__ float smw[41][64];
    const int b  = blockIdx.z;
    const int t0 = blockIdx.y * 128;
    const int d0 = blockIdx.x * 64;
    const int tid = threadIdx.x;

    for (int idx = tid; idx < 41 * 64; idx += 256) {
        int r = idx >> 6, c = idx & 63;
        smw[r][c] = mw[r * 1024 + d0 + c];
    }
    {
        const int row0 = tid >> 3;
        const int col8 = (tid & 7) * 8;
        #pragma unroll
        for (int i = 0; i < 6; ++i) {
            const int row = row0 + i * 32;
            if (row < FS_ROWS) {
                const int t = t0 + row - 39;
                u16x8 v = {0, 0, 0, 0, 0, 0, 0, 0};
                if (t >= 0)
                    v = *(const u16x8*)(p + ((long)b * T + t) * 1024 + d0 + col8);
                *(u16x8*)(&sp[row][col8]) = v;
            }
        }
    }
    __syncthreads();

    const int lane = tid & 63, wv = tid >> 6;
    const int d = d0 + lane;

    float m[40];
    #pragma unroll
    for (int l = 0; l < 40; ++l) m[l] = smw[l + 1][lane];
    const float m0v = smw[0][lane];
    const float tot = total[b * 1024 + d];

    #pragma unroll
    for (int pass = 0; pass < 2; ++pass) {
        const int obase = wv * 32 + pass * 16;
        float w[55];
        #pragma unroll
        for (int j = 0; j < 55; ++j) w[j] = bf2f(sp[obase + j][lane]);

        float acc[16];
        #pragma unroll
        for (int s = 0; s < 16; ++s) acc[s] = 0.f;
        #pragma unroll
        for (int lag = 0; lag < 40; ++lag) {
            const float mm = m[lag];
            #pragma unroll
            for (int s = 0; s < 16; ++s)
                acc[s] = fmaf(mm, w[s + 39 - lag], acc[s]);
        }

        float accw[16];
        {
            float S = 0.f;
            #pragma unroll
            for (int j = 0; j < 40; ++j) S += w[j];
            accw[0] = S;
            #pragma unroll
            for (int s = 1; s < 16; ++s) accw[s] = accw[s - 1] + w[s + 39] - w[s - 1];
        }

        unsigned short* ob = p2 + ((long)b * T + t0 + obase) * 1024 + d;
        #pragma unroll
        for (int s = 0; s < 16; ++s)
            ob[(long)s * 1024] = f2bf(acc[s] + m0v * (tot - accw[s]));
    }
}

// ---------- launch ----------
extern "C" void kernel_launch(void* const* d_in, const int* in_sizes, int n_in,
                              void* d_out, int out_size, void* d_ws, size_t ws_size,
                              hipStream_t stream) {
    const float* x  = (const float*)d_in[0];
    const float* W1 = (const float*)d_in[1];
    const float* b1 = (const float*)d_in[2];
    const float* W2 = (const float*)d_in[3];
    const float* b2 = (const float*)d_in[4];
    const float* mw = (const float*)d_in[5];
    float* out = (float*)d_out;

    const int B = 8, T = 2048;
    const long M = (long)B * T;          // 16384 rows
    const int N = 1024, K = 1024;

    char* ws = (char*)d_ws;
    unsigned short* p2_bf  = (unsigned short*)(ws);                 // old x_bf region
    unsigned short* W1t    = (unsigned short*)(ws + 33554432L);
    unsigned short* W2t    = (unsigned short*)(ws + 35651584L);
    unsigned short* p_bf   = (unsigned short*)(ws + 37748736L);
    float*          totals = (float*)(ws + 71303168L);

    k_transpose_bf16<<<dim3(16, 16, 2), 256, 0, stream>>>(W1, W1t, W2, W2t);

    hipMemsetAsync(totals, 0, B * 1024 * sizeof(float), stream);

    // GEMM1: A = x (fp32, fused cvt), fused column sums
    k_gemm256<1, 1, 1><<<dim3((int)((M / 256) * (N / 256))), 512, 0, stream>>>(
        nullptr, x, W1t, b1, (void*)p_bf, totals, (int)M, N, K);

    k_fsmn<<<dim3(1024 / 64, T / 128, B), 256, 0, stream>>>(p_bf, mw, totals, p2_bf, T);

    // GEMM2: A = p2 (bf16), fp32 out
    k_gemm256<0, 0, 0><<<dim3((int)((M / 256) * (N / 256))), 512, 0, stream>>>(
        p2_bf, nullptr, W2t, b2, (void*)out, nullptr, (int)M, N, K);
}